// Round 5
// baseline (257.544 us; speedup 1.0000x reference)
//
#include <hip/hip_runtime.h>
#include <hip/hip_bf16.h>

// Static problem config (matches reference)
#define RB 20
#define RA 19
#define NPT (RB*RA)       // 380 grid points
#define DZ 25             // (LZ+1)^2
#define DIN 9             // (L1+1)^2 == (L2+1)^2
#define MULT 128
#define CH 128

// ---------------------------------------------------------------------------
// Kernel 0: on-device input dtype detection (1 = bf16 storage, 0 = fp32).
__global__ void detect_kernel(const unsigned int* __restrict__ x, int* __restrict__ flag) {
    if (threadIdx.x == 0 && blockIdx.x == 0) {
        int votes = 0;
        for (int i = 0; i < 256; ++i) {
            unsigned int u = x[i];
            int e_lo = (u >> 7) & 0xff;
            int e_hi = (u >> 23) & 0xff;
            bool lo_ok = (e_lo >= 96 && e_lo <= 159) || ((u & 0xffffu) == 0u);
            bool hi_ok = (e_hi >= 96 && e_hi <= 159) || ((u >> 16) == 0u);
            if (lo_ok && hi_ok) ++votes;
        }
        *flag = (votes >= 192) ? 1 : 0;
    }
}

// Associated Legendre P_l^m(x), Condon-Shortley phase, double precision
static __device__ double alp_d(int l, int m, double x) {
    double pmm = 1.0;
    if (m > 0) {
        double df = 1.0;
        for (int i = 1; i < 2 * m; i += 2) df *= (double)i;   // (2m-1)!!
        pmm = ((m & 1) ? -1.0 : 1.0) * df * pow(1.0 - x * x, 0.5 * (double)m);
    }
    if (l == m) return pmm;
    double pmmp1 = x * (2.0 * m + 1.0) * pmm;
    if (l == m + 1) return pmmp1;
    double p = 0.0;
    for (int ll = m + 2; ll <= l; ++ll) {
        p = ((2.0 * ll - 1.0) * x * pmmp1 - (double)(ll + m - 1) * pmm) / (double)(ll - m);
        pmm = pmmp1;
        pmmp1 = p;
    }
    return p;
}

// ---------------------------------------------------------------------------
// Kernel 1: dense real-Gaunt table G[d][d1*9+d2] built from the reference's
// own quadrature (exact identity: z_d = sum_{d1,d2} G * xc_d1 * yc_d2).
// grid = 25 blocks (one per output d), 256 threads.
__global__ void gaunt_init_kernel(float* __restrict__ gG) {
    __shared__ float  Yt[DZ][NPT];     // 38 KB
    __shared__ double qws[NPT];        // 3 KB
    const int tid = threadIdx.x;
    const double PI = 3.14159265358979323846;

    for (int pt = tid; pt < NPT; pt += blockDim.x) {
        int b = pt / RA, a = pt - b * RA;
        // Gauss-Legendre node via Newton (node ordering irrelevant: only summed)
        double xg = cos(PI * (b + 0.75) / (RB + 0.5));
        double dp = 0.0;
        for (int it = 0; it < 20; ++it) {
            double p0 = 1.0, p1 = xg;
            for (int k = 2; k <= RB; ++k) {
                double p2 = ((2.0 * k - 1.0) * xg * p1 - (k - 1.0) * p0) / (double)k;
                p0 = p1; p1 = p2;
            }
            dp = RB * (xg * p1 - p0) / (xg * xg - 1.0);
            xg -= p1 / dp;
        }
        {   // final derivative at converged node
            double p0 = 1.0, p1 = xg;
            for (int k = 2; k <= RB; ++k) {
                double p2 = ((2.0 * k - 1.0) * xg * p1 - (k - 1.0) * p0) / (double)k;
                p0 = p1; p1 = p2;
            }
            dp = RB * (xg * p1 - p0) / (xg * xg - 1.0);
        }
        double wq = 2.0 / ((1.0 - xg * xg) * dp * dp);
        qws[pt] = wq * (2.0 * PI / (double)RA);

        double alpha = 2.0 * PI * (double)a / (double)RA;
        for (int l = 0; l <= 4; ++l) {
            for (int m = -l; m <= l; ++m) {
                int am = m < 0 ? -m : m;
                double fr = 1.0;                       // (l+am)!/(l-am)!
                for (int i = l - am + 1; i <= l + am; ++i) fr *= (double)i;
                double nlm = sqrt((2.0 * l + 1.0) / (4.0 * PI) / fr);
                double P = alp_d(l, am, xg);
                double ang;
                if (m == 0)      ang = 1.0;
                else if (m > 0)  ang = sqrt(2.0) * cos((double)m * alpha);
                else             ang = sqrt(2.0) * sin((double)am * alpha);
                Yt[l * l + l + m][pt] = (float)(nlm * P * ang);
            }
        }
    }
    __syncthreads();

    const int d = blockIdx.x;
    if (tid < DIN * DIN) {
        int d1 = tid / DIN, d2 = tid - DIN * d1;
        double s = 0.0;
        for (int p = 0; p < NPT; ++p)
            s += (double)Yt[d][p] * (double)Yt[d1][p] * (double)Yt[d2][p] * qws[p];
        gG[d * (DIN * DIN) + tid] = (float)s;
    }
}

// ---------------------------------------------------------------------------
// Kernel 2: fused per-node pipeline, one block per node. FP32 OUTPUT.
__global__ __launch_bounds__(256) void gaunt_main_kernel(
    const void* __restrict__ xg, const void* __restrict__ yg,
    const void* __restrict__ wxg, const void* __restrict__ wyg,
    const void* __restrict__ wzg, float* __restrict__ outg,
    const float* __restrict__ gG, const int* __restrict__ flagp) {

    // LDS pool (floats):
    //  [0    .. 2025) sG      dense Gaunt
    //  [2028 .. 3180) sX  [d][m]   (stage A/B)   -- later aliased by sOut
    //  [3180 .. 4332) sY  [d][m]   (stage A/B)   -- later aliased by sOut
    //  [4332 .. 5484) sXc [d][c]   (stage B/C)   -- later aliased by sOut
    //  [5484 .. 6636) sYc [d][c]   (stage B/C)   -- later aliased by sOut
    //  [6640 .. 9840) sZ  [d][c]   (stage C/D)
    //  [2028 .. 5228) sOut [e*25+d] (stage D/E, aliases sX..sYc, 16B-aligned)
    __shared__ __align__(16) float pool[9840];
    float* sG   = pool;
    float* sX   = pool + 2028;
    float* sY   = pool + 3180;
    float* sXc  = pool + 4332;
    float* sYc  = pool + 5484;
    float* sZ   = pool + 6640;
    float* sOut = pool + 2028;

    const int tid = threadIdx.x;
    const int n = blockIdx.x;
    const int isbf = *flagp;                   // wave-uniform
    const float s128 = 0.08838834764831845f;   // 1/sqrt(128)

    for (int i = tid; i < DZ * DIN * DIN; i += 256) sG[i] = gG[i];

    // Stage A: load x,y ([m][d] layout) -> LDS transposed [d][m], fp32
    if (isbf) {
        const unsigned short* xp = (const unsigned short*)xg + n * (MULT * DIN);
        const unsigned short* yp = (const unsigned short*)yg + n * (MULT * DIN);
        for (int i = tid; i < 2 * MULT * DIN; i += 256) {
            int isY = i >= MULT * DIN;
            int e = isY ? i - MULT * DIN : i;
            unsigned int u = (unsigned int)(isY ? yp[e] : xp[e]);
            int m = e / 9, d = e - 9 * m;
            (isY ? sY : sX)[d * MULT + m] = __uint_as_float(u << 16);
        }
    } else {
        const float* xp = (const float*)xg + n * (MULT * DIN);
        const float* yp = (const float*)yg + n * (MULT * DIN);
        for (int i = tid; i < 2 * MULT * DIN; i += 256) {
            int isY = i >= MULT * DIN;
            int e = isY ? i - MULT * DIN : i;
            float v = isY ? yp[e] : xp[e];
            int m = e / 9, d = e - 9 * m;
            (isY ? sY : sX)[d * MULT + m] = v;
        }
    }
    __syncthreads();

    // Stage B: per-l linear_in.  xc[c,d] = (1/sqrt(128)) sum_m x[m,d] w[l(d)][m,c]
    for (int idx = tid; idx < 576; idx += 256) {
        int isY = idx >= 288;
        int r = isY ? idx - 288 : idx;
        int d = r >> 5;
        int c0 = (r & 31) << 2;
        int l = (d == 0) ? 0 : (d < 4 ? 1 : 2);
        const float* src = (isY ? sY : sX) + d * MULT;
        float a0 = 0.f, a1 = 0.f, a2 = 0.f, a3 = 0.f;
        if (isbf) {
            const unsigned short* w = (const unsigned short*)(isY ? wyg : wxg) + l * (MULT * CH);
            for (int m = 0; m < MULT; ++m) {
                float xv = src[m];
                uint2 w4 = *(const uint2*)(w + (m << 7) + c0);
                a0 = fmaf(xv, __uint_as_float(w4.x << 16), a0);
                a1 = fmaf(xv, __uint_as_float(w4.x & 0xffff0000u), a1);
                a2 = fmaf(xv, __uint_as_float(w4.y << 16), a2);
                a3 = fmaf(xv, __uint_as_float(w4.y & 0xffff0000u), a3);
            }
        } else {
            const float* w = (const float*)(isY ? wyg : wxg) + l * (MULT * CH);
            for (int m = 0; m < MULT; ++m) {
                float xv = src[m];
                float4 w4 = *(const float4*)(w + (m << 7) + c0);
                a0 = fmaf(xv, w4.x, a0);
                a1 = fmaf(xv, w4.y, a1);
                a2 = fmaf(xv, w4.z, a2);
                a3 = fmaf(xv, w4.w, a3);
            }
        }
        float* dst = (isY ? sYc : sXc) + d * CH + c0;
        dst[0] = a0 * s128; dst[1] = a1 * s128;
        dst[2] = a2 * s128; dst[3] = a3 * s128;
    }
    __syncthreads();

    // Stage C: dense Gaunt contraction  z[c,d] = sum_{d1,d2} G[d][d1,d2] xc[d1,c] yc[d2,c]
    {
        int c = tid & 127;
        int half = tid >> 7;
        int dstart = half ? 13 : 0;
        int dend   = half ? 25 : 13;
        for (int d = dstart; d < dend; ++d) {
            const float* g = sG + d * (DIN * DIN);
            float acc = 0.f;
            for (int d1 = 0; d1 < DIN; ++d1) {
                float xv = sXc[d1 * CH + c];
                #pragma unroll
                for (int d2 = 0; d2 < DIN; ++d2)
                    acc = fmaf(g[d1 * DIN + d2] * xv, sYc[d2 * CH + c], acc);
            }
            sZ[d * CH + c] = acc;
        }
    }
    __syncthreads();   // sX/sY/sXc/sYc now dead; sOut may alias them

    // Stage D: per-l linear_out.  out[e,d] = (1/sqrt(128)) sum_c z[c,d] wz[l(d)][c,e]
    for (int idx = tid; idx < 800; idx += 256) {
        int d = idx >> 5;
        int e0 = (idx & 31) << 2;
        int l = (d == 0) ? 0 : (d < 4) ? 1 : (d < 9) ? 2 : (d < 16) ? 3 : 4;
        const float* zrow = sZ + d * CH;
        float a0 = 0.f, a1 = 0.f, a2 = 0.f, a3 = 0.f;
        if (isbf) {
            const unsigned short* w = (const unsigned short*)wzg + l * (CH * CH);
            for (int c = 0; c < CH; ++c) {
                float zv = zrow[c];
                uint2 w4 = *(const uint2*)(w + (c << 7) + e0);
                a0 = fmaf(zv, __uint_as_float(w4.x << 16), a0);
                a1 = fmaf(zv, __uint_as_float(w4.x & 0xffff0000u), a1);
                a2 = fmaf(zv, __uint_as_float(w4.y << 16), a2);
                a3 = fmaf(zv, __uint_as_float(w4.y & 0xffff0000u), a3);
            }
        } else {
            const float* w = (const float*)wzg + l * (CH * CH);
            for (int c = 0; c < CH; ++c) {
                float zv = zrow[c];
                float4 w4 = *(const float4*)(w + (c << 7) + e0);
                a0 = fmaf(zv, w4.x, a0);
                a1 = fmaf(zv, w4.y, a1);
                a2 = fmaf(zv, w4.z, a2);
                a3 = fmaf(zv, w4.w, a3);
            }
        }
        sOut[(e0 + 0) * DZ + d] = a0 * s128;
        sOut[(e0 + 1) * DZ + d] = a1 * s128;
        sOut[(e0 + 2) * DZ + d] = a2 * s128;
        sOut[(e0 + 3) * DZ + d] = a3 * s128;
    }
    __syncthreads();

    // Stage E: coalesced float4 store of the node's 3200 fp32 outputs
    float* po = outg + n * (CH * DZ);
    for (int j = tid; j < (CH * DZ) / 4; j += 256)
        *(float4*)(po + 4 * j) = *(const float4*)(sOut + 4 * j);
}

extern "C" void kernel_launch(void* const* d_in, const int* in_sizes, int n_in,
                              void* d_out, int out_size, void* d_ws, size_t ws_size,
                              hipStream_t stream) {
    float* gG   = (float*)d_ws;                 // 2025 floats (dense Gaunt)
    int*   flag = (int*)((char*)d_ws + 8192);

    int N = in_sizes[0] / (MULT * DIN);         // batch from harness

    hipLaunchKernelGGL(detect_kernel, dim3(1), dim3(64), 0, stream,
                       (const unsigned int*)d_in[0], flag);
    hipLaunchKernelGGL(gaunt_init_kernel, dim3(DZ), dim3(256), 0, stream, gG);
    hipLaunchKernelGGL(gaunt_main_kernel, dim3(N), dim3(256), 0, stream,
                       d_in[0], d_in[1], d_in[2], d_in[3], d_in[4],
                       (float*)d_out, gG, flag);
}

// Round 6
// 151.261 us; speedup vs baseline: 1.7026x; 1.7026x over previous
//
#include <hip/hip_runtime.h>

// Static problem config (matches reference)
#define RB 20
#define RA 19
#define NPT (RB*RA)       // 380 grid points
#define DZ 25             // (LZ+1)^2
#define DIN 9             // (L1+1)^2 == (L2+1)^2
#define MULT 128
#define CH 128

// ---------------------------------------------------------------------------
// Kernel 1: transposed dense real-Gaunt table Gt[d1*9+d2][28] (entry d at
// [pr*28+d]) built from the reference's own quadrature. No fp64 pow/sin/cos
// in the lm loops (multiply-only recurrences): ~10x faster than round-5 init.
// grid = 25 blocks (one per output d), 128 threads.
__global__ __launch_bounds__(128) void gaunt_init_kernel(float* __restrict__ gGt) {
    __shared__ float  Yt[DZ][NPT];     // 38 KB
    __shared__ double qws[NPT];        // 3 KB
    const int tid = threadIdx.x;
    const double PI = 3.14159265358979323846;

    for (int pt = tid; pt < NPT; pt += 128) {
        int b = pt / RA, a = pt - b * RA;
        // Gauss-Legendre node via Newton (ordering irrelevant: only summed)
        double xg = cos(PI * (b + 0.75) / (RB + 0.5));
        double dp = 0.0;
        for (int it = 0; it < 8; ++it) {
            double p0 = 1.0, p1 = xg;
            for (int k = 2; k <= RB; ++k) {
                double p2 = ((2.0*k - 1.0)*xg*p1 - (k - 1.0)*p0) / (double)k;
                p0 = p1; p1 = p2;
            }
            dp = RB * (xg*p1 - p0) / (xg*xg - 1.0);
            xg -= p1 / dp;
        }
        {   // final derivative at converged node
            double p0 = 1.0, p1 = xg;
            for (int k = 2; k <= RB; ++k) {
                double p2 = ((2.0*k - 1.0)*xg*p1 - (k - 1.0)*p0) / (double)k;
                p0 = p1; p1 = p2;
            }
            dp = RB * (xg*p1 - p0) / (xg*xg - 1.0);
        }
        qws[pt] = 2.0 / ((1.0 - xg*xg)*dp*dp) * (2.0*PI/(double)RA);

        double ct = xg, st = sqrt(1.0 - ct*ct);
        double alpha = 2.0*PI*(double)a/(double)RA;
        double c1 = cos(alpha), s1 = sin(alpha);
        double ca[5], sa[5];
        ca[0] = 1.0; sa[0] = 0.0; ca[1] = c1; sa[1] = s1;
        for (int m = 2; m <= 4; ++m) {
            ca[m] = ca[m-1]*c1 - sa[m-1]*s1;
            sa[m] = sa[m-1]*c1 + ca[m-1]*s1;
        }
        // Associated Legendre P[l][m], Condon-Shortley, multiply-only
        double P[5][5];
        double pmm = 1.0;
        for (int m = 0; m <= 4; ++m) {
            if (m > 0) pmm = pmm * (-(2.0*m - 1.0)) * st;   // (-1)^m (2m-1)!! st^m
            P[m][m] = pmm;
            if (m < 4) {
                double pp = pmm, pc = ct*(2.0*m + 1.0)*pmm;
                P[m+1][m] = pc;
                for (int l = m + 2; l <= 4; ++l) {
                    double pn = ((2.0*l - 1.0)*ct*pc - (double)(l + m - 1)*pp) / (double)(l - m);
                    P[l][m] = pn; pp = pc; pc = pn;
                }
            }
        }
        for (int l = 0; l <= 4; ++l)
            for (int m = -l; m <= l; ++m) {
                int am = m < 0 ? -m : m;
                double fr = 1.0;                       // (l+am)!/(l-am)!
                for (int i = l - am + 1; i <= l + am; ++i) fr *= (double)i;
                double nlm = sqrt((2.0*l + 1.0) / (4.0*PI) / fr);
                double ang = (m == 0) ? 1.0
                           : (m > 0 ? sqrt(2.0)*ca[am] : sqrt(2.0)*sa[am]);
                Yt[l*l + l + m][pt] = (float)(nlm * P[l][am] * ang);
            }
    }
    __syncthreads();

    const int d = blockIdx.x;
    if (tid < 81) {
        int d1 = tid / 9, d2 = tid - 9*d1;
        double s = 0.0;
        for (int p = 0; p < NPT; ++p)
            s += (double)Yt[d][p] * (double)Yt[d1][p] * (double)Yt[d2][p] * qws[p];
        gGt[tid * 28 + d] = (float)s;     // transposed, padded rows of 28
    }
}

// ---------------------------------------------------------------------------
// Kernel 2: fused per-node pipeline, one block per node. fp32 in, fp32 out.
// Stage B/D restructured so each W_l matrix is read exactly once per block.
__global__ __launch_bounds__(256) void gaunt_main_kernel(
    const float* __restrict__ xg, const float* __restrict__ yg,
    const float* __restrict__ wxg, const float* __restrict__ wyg,
    const float* __restrict__ wzg, float* __restrict__ outg,
    const float* __restrict__ gGt) {

    // LDS pool (floats), 45936 B total:
    //  sGt  [0,     2268)   transposed Gaunt [81][28]
    //  sX   [2268,  3420)   x [d][m]
    //  sY   [3420,  4572)
    //  sXc  [4572,  5724)   xc [d][c]
    //  sYc  [5724,  6876)
    //  sZ   [6876, 11484)   z  [c][36]
    //  sOut [0,     3200)   out [e][25]  (aliases sGt+sX, dead after stage C)
    __shared__ __align__(16) float pool[11484];
    float* sGt  = pool;
    float* sX   = pool + 2268;
    float* sY   = pool + 3420;
    float* sXc  = pool + 4572;
    float* sYc  = pool + 5724;
    float* sZ   = pool + 6876;
    float* sOut = pool;

    const int tid = threadIdx.x;
    const int n = blockIdx.x;
    const float s128 = 0.08838834764831845f;   // 1/sqrt(128)

    for (int i = tid; i < 81*28; i += 256) sGt[i] = gGt[i];

    // Stage A: load x,y ([m][d]) -> LDS transposed [d][m]
    const float* xp = xg + n * (MULT * DIN);
    const float* yp = yg + n * (MULT * DIN);
    for (int i = tid; i < 2 * MULT * DIN; i += 256) {
        int isY = i >= MULT * DIN;
        int e = isY ? i - MULT * DIN : i;
        float v = isY ? yp[e] : xp[e];
        int m = e / 9, d = e - 9 * m;
        (isY ? sY : sX)[d * MULT + m] = v;
    }
    __syncthreads();

    // Stage B: per-l linear_in, each W_l read ONCE per block.
    // wave0: l=0 (both sides), wave1: l=1, waves2-3: l=2 side0/side1.
    if (tid < 64) {                 // l=0, d=0, 4-channel items
        int side = tid >> 5, c0 = (tid & 31) << 2;
        const float* w = (side ? wyg : wxg) + c0;
        const float* src = side ? sY : sX;      // d=0 row
        float a0=0.f, a1=0.f, a2=0.f, a3=0.f;
        for (int m = 0; m < MULT; ++m) {
            float4 w4 = *(const float4*)(w + (m << 7));
            float xv = src[m];
            a0 = fmaf(xv, w4.x, a0); a1 = fmaf(xv, w4.y, a1);
            a2 = fmaf(xv, w4.z, a2); a3 = fmaf(xv, w4.w, a3);
        }
        float* dst = (side ? sYc : sXc) + c0;
        dst[0]=a0*s128; dst[1]=a1*s128; dst[2]=a2*s128; dst[3]=a3*s128;
    } else if (tid < 128) {         // l=1, d=1..3, 4-channel items
        int t = tid - 64, side = t >> 5, c0 = (t & 31) << 2;
        const float* w = (side ? wyg : wxg) + 16384 + c0;
        const float* src = (side ? sY : sX) + 128;
        float acc[12];
        #pragma unroll
        for (int k = 0; k < 12; ++k) acc[k] = 0.f;
        for (int m = 0; m < MULT; ++m) {
            float4 w4 = *(const float4*)(w + (m << 7));
            float x0 = src[m], x1 = src[128 + m], x2 = src[256 + m];
            acc[0]=fmaf(x0,w4.x,acc[0]); acc[1]=fmaf(x0,w4.y,acc[1]);
            acc[2]=fmaf(x0,w4.z,acc[2]); acc[3]=fmaf(x0,w4.w,acc[3]);
            acc[4]=fmaf(x1,w4.x,acc[4]); acc[5]=fmaf(x1,w4.y,acc[5]);
            acc[6]=fmaf(x1,w4.z,acc[6]); acc[7]=fmaf(x1,w4.w,acc[7]);
            acc[8]=fmaf(x2,w4.x,acc[8]); acc[9]=fmaf(x2,w4.y,acc[9]);
            acc[10]=fmaf(x2,w4.z,acc[10]); acc[11]=fmaf(x2,w4.w,acc[11]);
        }
        float* dst = (side ? sYc : sXc);
        #pragma unroll
        for (int dd = 0; dd < 3; ++dd) {
            float4 r; r.x=acc[dd*4]*s128; r.y=acc[dd*4+1]*s128;
            r.z=acc[dd*4+2]*s128; r.w=acc[dd*4+3]*s128;
            *(float4*)(dst + (1 + dd)*128 + c0) = r;
        }
    } else {                        // l=2, d=4..8, 2-channel items
        int t = tid - 128, side = t >> 6, cp = (t & 63) << 1;
        const float* w = (side ? wyg : wxg) + 32768 + cp;
        const float* src = (side ? sY : sX) + 512;
        float acc[10];
        #pragma unroll
        for (int k = 0; k < 10; ++k) acc[k] = 0.f;
        for (int m = 0; m < MULT; ++m) {
            float2 w2 = *(const float2*)(w + (m << 7));
            float x0=src[m], x1=src[128+m], x2=src[256+m], x3=src[384+m], x4=src[512+m];
            acc[0]=fmaf(x0,w2.x,acc[0]); acc[1]=fmaf(x0,w2.y,acc[1]);
            acc[2]=fmaf(x1,w2.x,acc[2]); acc[3]=fmaf(x1,w2.y,acc[3]);
            acc[4]=fmaf(x2,w2.x,acc[4]); acc[5]=fmaf(x2,w2.y,acc[5]);
            acc[6]=fmaf(x3,w2.x,acc[6]); acc[7]=fmaf(x3,w2.y,acc[7]);
            acc[8]=fmaf(x4,w2.x,acc[8]); acc[9]=fmaf(x4,w2.y,acc[9]);
        }
        float* dst = (side ? sYc : sXc) + 512 + cp;
        #pragma unroll
        for (int dd = 0; dd < 5; ++dd) {
            float2 r; r.x = acc[dd*2]*s128; r.y = acc[dd*2+1]*s128;
            *(float2*)(dst + dd*128) = r;
        }
    }
    __syncthreads();

    // Stage C: dense Gaunt contraction via transposed G.
    // z[c][d] = sum_{d1,d2} Gt[d1*9+d2][d] * xc[d1][c] * yc[d2][c]
    {
        const int c = tid & 127, half = tid >> 7;
        float xr[9];
        #pragma unroll
        for (int d = 0; d < 9; ++d) xr[d] = sXc[d*128 + c];
        float acc[25];
        #pragma unroll
        for (int d = 0; d < 25; ++d) acc[d] = 0.f;

        #define C_BODY(D1) \
            for (int d2 = 0; d2 < 9; ++d2) { \
                float p = xr[D1] * sYc[d2*128 + c]; \
                const float* gt = sGt + ((D1)*9 + d2) * 28; \
                float4 g0=*(const float4*)gt,      g1=*(const float4*)(gt+4); \
                float4 g2=*(const float4*)(gt+8),  g3=*(const float4*)(gt+12); \
                float4 g4=*(const float4*)(gt+16), g5=*(const float4*)(gt+20); \
                float  g6=gt[24]; \
                acc[0]=fmaf(p,g0.x,acc[0]);  acc[1]=fmaf(p,g0.y,acc[1]); \
                acc[2]=fmaf(p,g0.z,acc[2]);  acc[3]=fmaf(p,g0.w,acc[3]); \
                acc[4]=fmaf(p,g1.x,acc[4]);  acc[5]=fmaf(p,g1.y,acc[5]); \
                acc[6]=fmaf(p,g1.z,acc[6]);  acc[7]=fmaf(p,g1.w,acc[7]); \
                acc[8]=fmaf(p,g2.x,acc[8]);  acc[9]=fmaf(p,g2.y,acc[9]); \
                acc[10]=fmaf(p,g2.z,acc[10]); acc[11]=fmaf(p,g2.w,acc[11]); \
                acc[12]=fmaf(p,g3.x,acc[12]); acc[13]=fmaf(p,g3.y,acc[13]); \
                acc[14]=fmaf(p,g3.z,acc[14]); acc[15]=fmaf(p,g3.w,acc[15]); \
                acc[16]=fmaf(p,g4.x,acc[16]); acc[17]=fmaf(p,g4.y,acc[17]); \
                acc[18]=fmaf(p,g4.z,acc[18]); acc[19]=fmaf(p,g4.w,acc[19]); \
                acc[20]=fmaf(p,g5.x,acc[20]); acc[21]=fmaf(p,g5.y,acc[21]); \
                acc[22]=fmaf(p,g5.z,acc[22]); acc[23]=fmaf(p,g5.w,acc[23]); \
                acc[24]=fmaf(p,g6,acc[24]); \
            }
        if (half == 0) { C_BODY(0) C_BODY(1) C_BODY(2) C_BODY(3) C_BODY(4) }
        else           { C_BODY(5) C_BODY(6) C_BODY(7) C_BODY(8) }
        #undef C_BODY

        __syncthreads();
        if (half == 0) {
            #pragma unroll
            for (int d = 0; d < 25; ++d) sZ[c*36 + d] = acc[d];
        }
        __syncthreads();
        if (half == 1) {
            #pragma unroll
            for (int d = 0; d < 25; ++d) sZ[c*36 + d] += acc[d];
        }
    }
    __syncthreads();   // sGt/sX/sXc region now dead; sOut may alias

    // Stage D: per-l linear_out, each Wz_l read ONCE per block.
    if (tid < 32) {                 // l=0 (d=0), 4-channel
        int e0 = tid << 2;
        const float* w = wzg + e0;
        float a0=0.f,a1=0.f,a2=0.f,a3=0.f;
        for (int c = 0; c < CH; ++c) {
            float4 w4 = *(const float4*)(w + (c << 7));
            float zv = sZ[c*36];
            a0=fmaf(zv,w4.x,a0); a1=fmaf(zv,w4.y,a1);
            a2=fmaf(zv,w4.z,a2); a3=fmaf(zv,w4.w,a3);
        }
        sOut[(e0+0)*25] = a0*s128; sOut[(e0+1)*25] = a1*s128;
        sOut[(e0+2)*25] = a2*s128; sOut[(e0+3)*25] = a3*s128;
    } else if (tid < 64) {          // l=1 (d=1..3), 4-channel
        int e0 = (tid - 32) << 2;
        const float* w = wzg + 16384 + e0;
        float acc[12];
        #pragma unroll
        for (int k = 0; k < 12; ++k) acc[k] = 0.f;
        for (int c = 0; c < CH; ++c) {
            float4 w4 = *(const float4*)(w + (c << 7));
            const float* zr = sZ + c*36;
            float z1 = zr[1]; float2 z23 = *(const float2*)(zr + 2);
            acc[0]=fmaf(z1,w4.x,acc[0]);   acc[1]=fmaf(z1,w4.y,acc[1]);
            acc[2]=fmaf(z1,w4.z,acc[2]);   acc[3]=fmaf(z1,w4.w,acc[3]);
            acc[4]=fmaf(z23.x,w4.x,acc[4]); acc[5]=fmaf(z23.x,w4.y,acc[5]);
            acc[6]=fmaf(z23.x,w4.z,acc[6]); acc[7]=fmaf(z23.x,w4.w,acc[7]);
            acc[8]=fmaf(z23.y,w4.x,acc[8]); acc[9]=fmaf(z23.y,w4.y,acc[9]);
            acc[10]=fmaf(z23.y,w4.z,acc[10]); acc[11]=fmaf(z23.y,w4.w,acc[11]);
        }
        #pragma unroll
        for (int dd = 0; dd < 3; ++dd)
            #pragma unroll
            for (int k = 0; k < 4; ++k)
                sOut[(e0+k)*25 + 1 + dd] = acc[dd*4+k]*s128;
    } else if (tid < 128) {         // l=2 (d=4..8), 2-channel
        int ep = (tid - 64) << 1;
        const float* w = wzg + 32768 + ep;
        float acc[10];
        #pragma unroll
        for (int k = 0; k < 10; ++k) acc[k] = 0.f;
        for (int c = 0; c < CH; ++c) {
            float2 w2 = *(const float2*)(w + (c << 7));
            const float* zr = sZ + c*36;
            float4 z47 = *(const float4*)(zr + 4); float z8 = zr[8];
            acc[0]=fmaf(z47.x,w2.x,acc[0]); acc[1]=fmaf(z47.x,w2.y,acc[1]);
            acc[2]=fmaf(z47.y,w2.x,acc[2]); acc[3]=fmaf(z47.y,w2.y,acc[3]);
            acc[4]=fmaf(z47.z,w2.x,acc[4]); acc[5]=fmaf(z47.z,w2.y,acc[5]);
            acc[6]=fmaf(z47.w,w2.x,acc[6]); acc[7]=fmaf(z47.w,w2.y,acc[7]);
            acc[8]=fmaf(z8,w2.x,acc[8]);    acc[9]=fmaf(z8,w2.y,acc[9]);
        }
        #pragma unroll
        for (int dd = 0; dd < 5; ++dd) {
            sOut[(ep+0)*25 + 4 + dd] = acc[dd*2+0]*s128;
            sOut[(ep+1)*25 + 4 + dd] = acc[dd*2+1]*s128;
        }
    } else if (tid < 192) {         // l=3 (d=9..15), 2-channel
        int ep = (tid - 128) << 1;
        const float* w = wzg + 49152 + ep;
        float acc[14];
        #pragma unroll
        for (int k = 0; k < 14; ++k) acc[k] = 0.f;
        for (int c = 0; c < CH; ++c) {
            float2 w2 = *(const float2*)(w + (c << 7));
            const float* zr = sZ + c*36;
            float z9 = zr[9]; float2 zA = *(const float2*)(zr + 10);
            float4 zB = *(const float4*)(zr + 12);
            acc[0]=fmaf(z9,w2.x,acc[0]);   acc[1]=fmaf(z9,w2.y,acc[1]);
            acc[2]=fmaf(zA.x,w2.x,acc[2]); acc[3]=fmaf(zA.x,w2.y,acc[3]);
            acc[4]=fmaf(zA.y,w2.x,acc[4]); acc[5]=fmaf(zA.y,w2.y,acc[5]);
            acc[6]=fmaf(zB.x,w2.x,acc[6]); acc[7]=fmaf(zB.x,w2.y,acc[7]);
            acc[8]=fmaf(zB.y,w2.x,acc[8]); acc[9]=fmaf(zB.y,w2.y,acc[9]);
            acc[10]=fmaf(zB.z,w2.x,acc[10]); acc[11]=fmaf(zB.z,w2.y,acc[11]);
            acc[12]=fmaf(zB.w,w2.x,acc[12]); acc[13]=fmaf(zB.w,w2.y,acc[13]);
        }
        #pragma unroll
        for (int dd = 0; dd < 7; ++dd) {
            sOut[(ep+0)*25 + 9 + dd] = acc[dd*2+0]*s128;
            sOut[(ep+1)*25 + 9 + dd] = acc[dd*2+1]*s128;
        }
    } else {                        // l=4 (d=16..24), 2-channel
        int ep = (tid - 192) << 1;
        const float* w = wzg + 65536 + ep;
        float acc[18];
        #pragma unroll
        for (int k = 0; k < 18; ++k) acc[k] = 0.f;
        for (int c = 0; c < CH; ++c) {
            float2 w2 = *(const float2*)(w + (c << 7));
            const float* zr = sZ + c*36;
            float4 zA = *(const float4*)(zr + 16), zB = *(const float4*)(zr + 20);
            float z24 = zr[24];
            acc[0]=fmaf(zA.x,w2.x,acc[0]);  acc[1]=fmaf(zA.x,w2.y,acc[1]);
            acc[2]=fmaf(zA.y,w2.x,acc[2]);  acc[3]=fmaf(zA.y,w2.y,acc[3]);
            acc[4]=fmaf(zA.z,w2.x,acc[4]);  acc[5]=fmaf(zA.z,w2.y,acc[5]);
            acc[6]=fmaf(zA.w,w2.x,acc[6]);  acc[7]=fmaf(zA.w,w2.y,acc[7]);
            acc[8]=fmaf(zB.x,w2.x,acc[8]);  acc[9]=fmaf(zB.x,w2.y,acc[9]);
            acc[10]=fmaf(zB.y,w2.x,acc[10]); acc[11]=fmaf(zB.y,w2.y,acc[11]);
            acc[12]=fmaf(zB.z,w2.x,acc[12]); acc[13]=fmaf(zB.z,w2.y,acc[13]);
            acc[14]=fmaf(zB.w,w2.x,acc[14]); acc[15]=fmaf(zB.w,w2.y,acc[15]);
            acc[16]=fmaf(z24,w2.x,acc[16]);  acc[17]=fmaf(z24,w2.y,acc[17]);
        }
        #pragma unroll
        for (int dd = 0; dd < 9; ++dd) {
            sOut[(ep+0)*25 + 16 + dd] = acc[dd*2+0]*s128;
            sOut[(ep+1)*25 + 16 + dd] = acc[dd*2+1]*s128;
        }
    }
    __syncthreads();

    // Stage E: coalesced float4 store of the node's 3200 fp32 outputs
    float* po = outg + n * (CH * DZ);
    for (int j = tid; j < (CH * DZ) / 4; j += 256)
        *(float4*)(po + 4*j) = *(const float4*)(sOut + 4*j);
}

extern "C" void kernel_launch(void* const* d_in, const int* in_sizes, int n_in,
                              void* d_out, int out_size, void* d_ws, size_t ws_size,
                              hipStream_t stream) {
    float* gGt = (float*)d_ws;                  // 81*28 floats (transposed Gaunt)
    int N = in_sizes[0] / (MULT * DIN);         // batch from harness

    hipLaunchKernelGGL(gaunt_init_kernel, dim3(DZ), dim3(128), 0, stream, gGt);
    hipLaunchKernelGGL(gaunt_main_kernel, dim3(N), dim3(256), 0, stream,
                       (const float*)d_in[0], (const float*)d_in[1],
                       (const float*)d_in[2], (const float*)d_in[3],
                       (const float*)d_in[4], (float*)d_out, gGt);
}

// Round 7
// 143.154 us; speedup vs baseline: 1.7991x; 1.0566x over previous
//
#include <hip/hip_runtime.h>

// Static problem config (matches reference)
#define RB 20
#define RA 19
#define NPT (RB*RA)       // 380 grid points
#define DZ 25             // (LZ+1)^2
#define DIN 9             // (L1+1)^2 == (L2+1)^2
#define MULT 128
#define CH 128

// ---------------------------------------------------------------------------
// Kernel 1: transposed dense real-Gaunt table Gt[d1*9+d2][28] built from the
// reference's quadrature. ALL fp32 (hardware trig/sqrt, cheap divides): G
// error ~1e-6, irrelevant vs the 8.4e-2 threshold. 25 blocks x 128 threads.
__global__ __launch_bounds__(128) void gaunt_init_kernel(float* __restrict__ gGt) {
    __shared__ float Yt[DZ][NPT];     // 38 KB
    __shared__ float qws[NPT];
    const int tid = threadIdx.x;
    const float PI = 3.14159265358979323846f;

    for (int pt = tid; pt < NPT; pt += 128) {
        int b = pt / RA, a = pt - b * RA;
        // Gauss-Legendre node via Newton (ordering irrelevant: only summed)
        float xg = cosf(PI * (b + 0.75f) / (RB + 0.5f));
        float dp = 0.f;
        for (int it = 0; it < 5; ++it) {
            float p0 = 1.f, p1 = xg;
            for (int k = 2; k <= RB; ++k) {
                float p2 = ((2.f*k - 1.f)*xg*p1 - (k - 1.f)*p0) / (float)k;
                p0 = p1; p1 = p2;
            }
            dp = RB * (xg*p1 - p0) / (xg*xg - 1.f);
            xg -= p1 / dp;
        }
        {   // final derivative at converged node
            float p0 = 1.f, p1 = xg;
            for (int k = 2; k <= RB; ++k) {
                float p2 = ((2.f*k - 1.f)*xg*p1 - (k - 1.f)*p0) / (float)k;
                p0 = p1; p1 = p2;
            }
            dp = RB * (xg*p1 - p0) / (xg*xg - 1.f);
        }
        qws[pt] = 2.f / ((1.f - xg*xg)*dp*dp) * (2.f*PI/(float)RA);

        float ct = xg, st = sqrtf(fmaxf(0.f, 1.f - ct*ct));
        float alpha = 2.f*PI*(float)a/(float)RA;
        float c1 = cosf(alpha), s1 = sinf(alpha);
        float ca[5], sa[5];
        ca[0] = 1.f; sa[0] = 0.f; ca[1] = c1; sa[1] = s1;
        for (int m = 2; m <= 4; ++m) {
            ca[m] = ca[m-1]*c1 - sa[m-1]*s1;
            sa[m] = sa[m-1]*c1 + ca[m-1]*s1;
        }
        // Associated Legendre P[l][m], Condon-Shortley, multiply-only
        float P[5][5]; float pmm = 1.f;
        for (int m = 0; m <= 4; ++m) {
            if (m > 0) pmm *= -(2.f*m - 1.f) * st;
            P[m][m] = pmm;
            if (m < 4) {
                float pp = pmm, pc = ct*(2.f*m + 1.f)*pmm;
                P[m+1][m] = pc;
                for (int l = m + 2; l <= 4; ++l) {
                    float pn = ((2.f*l - 1.f)*ct*pc - (float)(l + m - 1)*pp) / (float)(l - m);
                    P[l][m] = pn; pp = pc; pc = pn;
                }
            }
        }
        for (int l = 0; l <= 4; ++l)
            for (int m = -l; m <= l; ++m) {
                int am = m < 0 ? -m : m;
                float fr = 1.f;
                for (int i = l - am + 1; i <= l + am; ++i) fr *= (float)i;
                float nlm = sqrtf((2.f*l + 1.f) / (4.f*PI) / fr);
                float ang = (m == 0) ? 1.f
                          : (m > 0 ? 1.41421356237f*ca[am] : 1.41421356237f*sa[am]);
                Yt[l*l + l + m][pt] = nlm * P[l][am] * ang;
            }
    }
    __syncthreads();

    const int d = blockIdx.x;
    if (tid < 81) {
        int d1 = tid / 9, d2 = tid - 9*d1;
        float s = 0.f;
        for (int p = 0; p < NPT; ++p)
            s += Yt[d][p] * Yt[d1][p] * Yt[d2][p] * qws[p];
        gGt[tid * 28 + d] = s;     // transposed, padded rows of 28
    }
}

// ---------------------------------------------------------------------------
// Kernel 2: fused per-node pipeline, one block per node. fp32 in/out.
// Weights read once per block; all weight loads batched 8-wide to keep
// many L2 loads in flight (the round-6 kernel was L2-latency-bound).
__global__ __launch_bounds__(256) void gaunt_main_kernel(
    const float* __restrict__ xg, const float* __restrict__ yg,
    const float* __restrict__ wxg, const float* __restrict__ wyg,
    const float* __restrict__ wzg, float* __restrict__ outg,
    const float* __restrict__ gGt) {

    // LDS pool (floats), 46080 B:
    //  sGt  [0,     2268)   transposed Gaunt [81][28]
    //  sX   [2268,  3438)   x [d][m] stride 130 (bank-conflict-free transpose)
    //  sY   [3438,  4608)
    //  sXc  [4608,  5760)   xc [d][c]
    //  sYc  [5760,  6912)
    //  sZ   [6912, 11520)   z  [c][36]
    //  sOut [0,     3200)   out [e][25]  (aliases sGt/sX, dead after stage C)
    __shared__ __align__(16) float pool[11520];
    float* sGt  = pool;
    float* sX   = pool + 2268;
    float* sY   = pool + 3438;
    float* sXc  = pool + 4608;
    float* sYc  = pool + 5760;
    float* sZ   = pool + 6912;
    float* sOut = pool;

    const int tid = threadIdx.x;
    const int n = blockIdx.x;
    const float s128 = 0.08838834764831845f;   // 1/sqrt(128)

    for (int i = tid; i < 81*28; i += 256) sGt[i] = gGt[i];

    // Stage A: load x,y ([m][d]) -> LDS transposed [d][m], stride 130
    const float* xp = xg + n * (MULT * DIN);
    const float* yp = yg + n * (MULT * DIN);
    for (int i = tid; i < 2 * MULT * DIN; i += 256) {
        int isY = i >= MULT * DIN;
        int e = isY ? i - MULT * DIN : i;
        float v = isY ? yp[e] : xp[e];
        int m = e / 9, d = e - 9 * m;
        (isY ? sY : sX)[d * 130 + m] = v;
    }
    __syncthreads();

    // Stage B: per-l linear_in, each W_l read ONCE per block, loads 8-batched.
    if (tid < 64) {                 // l=0, d=0
        int side = tid >> 5, c0 = (tid & 31) << 2;
        const float* w = (side ? wyg : wxg) + c0;
        const float* src = side ? sY : sX;
        float a0=0.f, a1=0.f, a2=0.f, a3=0.f;
        for (int m = 0; m < MULT; m += 8) {
            float4 wv[8];
            #pragma unroll
            for (int k = 0; k < 8; ++k) wv[k] = *(const float4*)(w + ((m+k) << 7));
            #pragma unroll
            for (int k = 0; k < 8; ++k) {
                float xv = src[m+k];
                a0=fmaf(xv,wv[k].x,a0); a1=fmaf(xv,wv[k].y,a1);
                a2=fmaf(xv,wv[k].z,a2); a3=fmaf(xv,wv[k].w,a3);
            }
        }
        float4 r; r.x=a0*s128; r.y=a1*s128; r.z=a2*s128; r.w=a3*s128;
        *(float4*)((side ? sYc : sXc) + c0) = r;
    } else if (tid < 128) {         // l=1, d=1..3
        int t = tid - 64, side = t >> 5, c0 = (t & 31) << 2;
        const float* w = (side ? wyg : wxg) + 16384 + c0;
        const float* src = (side ? sY : sX) + 130;
        float acc[12];
        #pragma unroll
        for (int k = 0; k < 12; ++k) acc[k] = 0.f;
        for (int m = 0; m < MULT; m += 8) {
            float4 wv[8];
            #pragma unroll
            for (int k = 0; k < 8; ++k) wv[k] = *(const float4*)(w + ((m+k) << 7));
            #pragma unroll
            for (int k = 0; k < 8; ++k) {
                float x0 = src[m+k], x1 = src[130+m+k], x2 = src[260+m+k];
                acc[0]=fmaf(x0,wv[k].x,acc[0]);  acc[1]=fmaf(x0,wv[k].y,acc[1]);
                acc[2]=fmaf(x0,wv[k].z,acc[2]);  acc[3]=fmaf(x0,wv[k].w,acc[3]);
                acc[4]=fmaf(x1,wv[k].x,acc[4]);  acc[5]=fmaf(x1,wv[k].y,acc[5]);
                acc[6]=fmaf(x1,wv[k].z,acc[6]);  acc[7]=fmaf(x1,wv[k].w,acc[7]);
                acc[8]=fmaf(x2,wv[k].x,acc[8]);  acc[9]=fmaf(x2,wv[k].y,acc[9]);
                acc[10]=fmaf(x2,wv[k].z,acc[10]); acc[11]=fmaf(x2,wv[k].w,acc[11]);
            }
        }
        float* dst = (side ? sYc : sXc);
        #pragma unroll
        for (int dd = 0; dd < 3; ++dd) {
            float4 r; r.x=acc[dd*4]*s128; r.y=acc[dd*4+1]*s128;
            r.z=acc[dd*4+2]*s128; r.w=acc[dd*4+3]*s128;
            *(float4*)(dst + (1 + dd)*128 + c0) = r;
        }
    } else {                        // l=2, d=4..8
        int t = tid - 128, side = t >> 6, cp = (t & 63) << 1;
        const float* w = (side ? wyg : wxg) + 32768 + cp;
        const float* src = (side ? sY : sX) + 520;
        float acc[10];
        #pragma unroll
        for (int k = 0; k < 10; ++k) acc[k] = 0.f;
        for (int m = 0; m < MULT; m += 8) {
            float2 wv[8];
            #pragma unroll
            for (int k = 0; k < 8; ++k) wv[k] = *(const float2*)(w + ((m+k) << 7));
            #pragma unroll
            for (int k = 0; k < 8; ++k) {
                float x0=src[m+k], x1=src[130+m+k], x2=src[260+m+k],
                      x3=src[390+m+k], x4=src[520+m+k];
                acc[0]=fmaf(x0,wv[k].x,acc[0]); acc[1]=fmaf(x0,wv[k].y,acc[1]);
                acc[2]=fmaf(x1,wv[k].x,acc[2]); acc[3]=fmaf(x1,wv[k].y,acc[3]);
                acc[4]=fmaf(x2,wv[k].x,acc[4]); acc[5]=fmaf(x2,wv[k].y,acc[5]);
                acc[6]=fmaf(x3,wv[k].x,acc[6]); acc[7]=fmaf(x3,wv[k].y,acc[7]);
                acc[8]=fmaf(x4,wv[k].x,acc[8]); acc[9]=fmaf(x4,wv[k].y,acc[9]);
            }
        }
        float* dst = (side ? sYc : sXc) + 512 + cp;
        #pragma unroll
        for (int dd = 0; dd < 5; ++dd) {
            float2 r; r.x = acc[dd*2]*s128; r.y = acc[dd*2+1]*s128;
            *(float2*)(dst + dd*128) = r;
        }
    }
    __syncthreads();

    // Stage C: dense Gaunt contraction via transposed G (x,y coeffs in regs).
    {
        const int c = tid & 127, half = tid >> 7;
        float xr[9], yr[9];
        #pragma unroll
        for (int d = 0; d < 9; ++d) { xr[d] = sXc[d*128 + c]; yr[d] = sYc[d*128 + c]; }
        float acc[25];
        #pragma unroll
        for (int d = 0; d < 25; ++d) acc[d] = 0.f;

        #define C_BODY(D1) \
            _Pragma("unroll") \
            for (int d2 = 0; d2 < 9; ++d2) { \
                float p = xr[D1] * yr[d2]; \
                const float* gt = sGt + ((D1)*9 + d2) * 28; \
                float4 g0=*(const float4*)gt,      g1=*(const float4*)(gt+4); \
                float4 g2=*(const float4*)(gt+8),  g3=*(const float4*)(gt+12); \
                float4 g4=*(const float4*)(gt+16), g5=*(const float4*)(gt+20); \
                float  g6=gt[24]; \
                acc[0]=fmaf(p,g0.x,acc[0]);  acc[1]=fmaf(p,g0.y,acc[1]); \
                acc[2]=fmaf(p,g0.z,acc[2]);  acc[3]=fmaf(p,g0.w,acc[3]); \
                acc[4]=fmaf(p,g1.x,acc[4]);  acc[5]=fmaf(p,g1.y,acc[5]); \
                acc[6]=fmaf(p,g1.z,acc[6]);  acc[7]=fmaf(p,g1.w,acc[7]); \
                acc[8]=fmaf(p,g2.x,acc[8]);  acc[9]=fmaf(p,g2.y,acc[9]); \
                acc[10]=fmaf(p,g2.z,acc[10]); acc[11]=fmaf(p,g2.w,acc[11]); \
                acc[12]=fmaf(p,g3.x,acc[12]); acc[13]=fmaf(p,g3.y,acc[13]); \
                acc[14]=fmaf(p,g3.z,acc[14]); acc[15]=fmaf(p,g3.w,acc[15]); \
                acc[16]=fmaf(p,g4.x,acc[16]); acc[17]=fmaf(p,g4.y,acc[17]); \
                acc[18]=fmaf(p,g4.z,acc[18]); acc[19]=fmaf(p,g4.w,acc[19]); \
                acc[20]=fmaf(p,g5.x,acc[20]); acc[21]=fmaf(p,g5.y,acc[21]); \
                acc[22]=fmaf(p,g5.z,acc[22]); acc[23]=fmaf(p,g5.w,acc[23]); \
                acc[24]=fmaf(p,g6,acc[24]); \
            }
        if (half == 0) { C_BODY(0) C_BODY(1) C_BODY(2) C_BODY(3) C_BODY(4) }
        else           { C_BODY(5) C_BODY(6) C_BODY(7) C_BODY(8) }
        #undef C_BODY

        if (half == 0) {
            #pragma unroll
            for (int d = 0; d < 25; ++d) sZ[c*36 + d] = acc[d];
        }
        __syncthreads();
        if (half == 1) {
            #pragma unroll
            for (int d = 0; d < 25; ++d) sZ[c*36 + d] += acc[d];
        }
    }
    __syncthreads();   // sGt/sX region now dead; sOut may alias

    // Stage D: per-l linear_out, each Wz_l read ONCE per block, loads 8-batched.
    if (tid < 32) {                 // l=0 (d=0)
        int e0 = tid << 2;
        const float* w = wzg + e0;
        float a0=0.f,a1=0.f,a2=0.f,a3=0.f;
        for (int c = 0; c < CH; c += 8) {
            float4 wv[8];
            #pragma unroll
            for (int k = 0; k < 8; ++k) wv[k] = *(const float4*)(w + ((c+k) << 7));
            #pragma unroll
            for (int k = 0; k < 8; ++k) {
                float zv = sZ[(c+k)*36];
                a0=fmaf(zv,wv[k].x,a0); a1=fmaf(zv,wv[k].y,a1);
                a2=fmaf(zv,wv[k].z,a2); a3=fmaf(zv,wv[k].w,a3);
            }
        }
        sOut[(e0+0)*25] = a0*s128; sOut[(e0+1)*25] = a1*s128;
        sOut[(e0+2)*25] = a2*s128; sOut[(e0+3)*25] = a3*s128;
    } else if (tid < 64) {          // l=1 (d=1..3)
        int e0 = (tid - 32) << 2;
        const float* w = wzg + 16384 + e0;
        float acc[12];
        #pragma unroll
        for (int k = 0; k < 12; ++k) acc[k] = 0.f;
        for (int c = 0; c < CH; c += 8) {
            float4 wv[8];
            #pragma unroll
            for (int k = 0; k < 8; ++k) wv[k] = *(const float4*)(w + ((c+k) << 7));
            #pragma unroll
            for (int k = 0; k < 8; ++k) {
                const float* zr = sZ + (c+k)*36;
                float z1 = zr[1]; float2 z23 = *(const float2*)(zr + 2);
                acc[0]=fmaf(z1,wv[k].x,acc[0]);    acc[1]=fmaf(z1,wv[k].y,acc[1]);
                acc[2]=fmaf(z1,wv[k].z,acc[2]);    acc[3]=fmaf(z1,wv[k].w,acc[3]);
                acc[4]=fmaf(z23.x,wv[k].x,acc[4]); acc[5]=fmaf(z23.x,wv[k].y,acc[5]);
                acc[6]=fmaf(z23.x,wv[k].z,acc[6]); acc[7]=fmaf(z23.x,wv[k].w,acc[7]);
                acc[8]=fmaf(z23.y,wv[k].x,acc[8]); acc[9]=fmaf(z23.y,wv[k].y,acc[9]);
                acc[10]=fmaf(z23.y,wv[k].z,acc[10]); acc[11]=fmaf(z23.y,wv[k].w,acc[11]);
            }
        }
        #pragma unroll
        for (int dd = 0; dd < 3; ++dd)
            #pragma unroll
            for (int k = 0; k < 4; ++k)
                sOut[(e0+k)*25 + 1 + dd] = acc[dd*4+k]*s128;
    } else if (tid < 128) {         // l=2 (d=4..8)
        int ep = (tid - 64) << 1;
        const float* w = wzg + 32768 + ep;
        float acc[10];
        #pragma unroll
        for (int k = 0; k < 10; ++k) acc[k] = 0.f;
        for (int c = 0; c < CH; c += 8) {
            float2 wv[8];
            #pragma unroll
            for (int k = 0; k < 8; ++k) wv[k] = *(const float2*)(w + ((c+k) << 7));
            #pragma unroll
            for (int k = 0; k < 8; ++k) {
                const float* zr = sZ + (c+k)*36;
                float4 z47 = *(const float4*)(zr + 4); float z8 = zr[8];
                acc[0]=fmaf(z47.x,wv[k].x,acc[0]); acc[1]=fmaf(z47.x,wv[k].y,acc[1]);
                acc[2]=fmaf(z47.y,wv[k].x,acc[2]); acc[3]=fmaf(z47.y,wv[k].y,acc[3]);
                acc[4]=fmaf(z47.z,wv[k].x,acc[4]); acc[5]=fmaf(z47.z,wv[k].y,acc[5]);
                acc[6]=fmaf(z47.w,wv[k].x,acc[6]); acc[7]=fmaf(z47.w,wv[k].y,acc[7]);
                acc[8]=fmaf(z8,wv[k].x,acc[8]);    acc[9]=fmaf(z8,wv[k].y,acc[9]);
            }
        }
        #pragma unroll
        for (int dd = 0; dd < 5; ++dd) {
            sOut[(ep+0)*25 + 4 + dd] = acc[dd*2+0]*s128;
            sOut[(ep+1)*25 + 4 + dd] = acc[dd*2+1]*s128;
        }
    } else if (tid < 192) {         // l=3 (d=9..15)
        int ep = (tid - 128) << 1;
        const float* w = wzg + 49152 + ep;
        float acc[14];
        #pragma unroll
        for (int k = 0; k < 14; ++k) acc[k] = 0.f;
        for (int c = 0; c < CH; c += 8) {
            float2 wv[8];
            #pragma unroll
            for (int k = 0; k < 8; ++k) wv[k] = *(const float2*)(w + ((c+k) << 7));
            #pragma unroll
            for (int k = 0; k < 8; ++k) {
                const float* zr = sZ + (c+k)*36;
                float z9 = zr[9]; float2 zA = *(const float2*)(zr + 10);
                float4 zB = *(const float4*)(zr + 12);
                acc[0]=fmaf(z9,wv[k].x,acc[0]);    acc[1]=fmaf(z9,wv[k].y,acc[1]);
                acc[2]=fmaf(zA.x,wv[k].x,acc[2]);  acc[3]=fmaf(zA.x,wv[k].y,acc[3]);
                acc[4]=fmaf(zA.y,wv[k].x,acc[4]);  acc[5]=fmaf(zA.y,wv[k].y,acc[5]);
                acc[6]=fmaf(zB.x,wv[k].x,acc[6]);  acc[7]=fmaf(zB.x,wv[k].y,acc[7]);
                acc[8]=fmaf(zB.y,wv[k].x,acc[8]);  acc[9]=fmaf(zB.y,wv[k].y,acc[9]);
                acc[10]=fmaf(zB.z,wv[k].x,acc[10]); acc[11]=fmaf(zB.z,wv[k].y,acc[11]);
                acc[12]=fmaf(zB.w,wv[k].x,acc[12]); acc[13]=fmaf(zB.w,wv[k].y,acc[13]);
            }
        }
        #pragma unroll
        for (int dd = 0; dd < 7; ++dd) {
            sOut[(ep+0)*25 + 9 + dd] = acc[dd*2+0]*s128;
            sOut[(ep+1)*25 + 9 + dd] = acc[dd*2+1]*s128;
        }
    } else {                        // l=4 (d=16..24)
        int ep = (tid - 192) << 1;
        const float* w = wzg + 65536 + ep;
        float acc[18];
        #pragma unroll
        for (int k = 0; k < 18; ++k) acc[k] = 0.f;
        for (int c = 0; c < CH; c += 8) {
            float2 wv[8];
            #pragma unroll
            for (int k = 0; k < 8; ++k) wv[k] = *(const float2*)(w + ((c+k) << 7));
            #pragma unroll
            for (int k = 0; k < 8; ++k) {
                const float* zr = sZ + (c+k)*36;
                float4 zA = *(const float4*)(zr + 16), zB = *(const float4*)(zr + 20);
                float z24 = zr[24];
                acc[0]=fmaf(zA.x,wv[k].x,acc[0]);   acc[1]=fmaf(zA.x,wv[k].y,acc[1]);
                acc[2]=fmaf(zA.y,wv[k].x,acc[2]);   acc[3]=fmaf(zA.y,wv[k].y,acc[3]);
                acc[4]=fmaf(zA.z,wv[k].x,acc[4]);   acc[5]=fmaf(zA.z,wv[k].y,acc[5]);
                acc[6]=fmaf(zA.w,wv[k].x,acc[6]);   acc[7]=fmaf(zA.w,wv[k].y,acc[7]);
                acc[8]=fmaf(zB.x,wv[k].x,acc[8]);   acc[9]=fmaf(zB.x,wv[k].y,acc[9]);
                acc[10]=fmaf(zB.y,wv[k].x,acc[10]); acc[11]=fmaf(zB.y,wv[k].y,acc[11]);
                acc[12]=fmaf(zB.z,wv[k].x,acc[12]); acc[13]=fmaf(zB.z,wv[k].y,acc[13]);
                acc[14]=fmaf(zB.w,wv[k].x,acc[14]); acc[15]=fmaf(zB.w,wv[k].y,acc[15]);
                acc[16]=fmaf(z24,wv[k].x,acc[16]);  acc[17]=fmaf(z24,wv[k].y,acc[17]);
            }
        }
        #pragma unroll
        for (int dd = 0; dd < 9; ++dd) {
            sOut[(ep+0)*25 + 16 + dd] = acc[dd*2+0]*s128;
            sOut[(ep+1)*25 + 16 + dd] = acc[dd*2+1]*s128;
        }
    }
    __syncthreads();

    // Stage E: coalesced float4 store of the node's 3200 fp32 outputs
    float* po = outg + n * (CH * DZ);
    for (int j = tid; j < (CH * DZ) / 4; j += 256)
        *(float4*)(po + 4*j) = *(const float4*)(sOut + 4*j);
}

extern "C" void kernel_launch(void* const* d_in, const int* in_sizes, int n_in,
                              void* d_out, int out_size, void* d_ws, size_t ws_size,
                              hipStream_t stream) {
    float* gGt = (float*)d_ws;                  // 81*28 floats (transposed Gaunt)
    int N = in_sizes[0] / (MULT * DIN);         // batch from harness

    hipLaunchKernelGGL(gaunt_init_kernel, dim3(DZ), dim3(128), 0, stream, gGt);
    hipLaunchKernelGGL(gaunt_main_kernel, dim3(N), dim3(256), 0, stream,
                       (const float*)d_in[0], (const float*)d_in[1],
                       (const float*)d_in[2], (const float*)d_in[3],
                       (const float*)d_in[4], (float*)d_out, gGt);
}